// Round 3
// baseline (142.292 us; speedup 1.0000x reference)
//
#include <hip/hip_runtime.h>

#define BB 8
#define SS 2048
#define DD 128
#define ROWS 16            // q rows per block
#define NW 8               // waves per block (512 threads)
#define CTW 16             // col-tiles (of 16) per wave -> 256 cols/wave

typedef short bf16x8 __attribute__((ext_vector_type(8)));
typedef float f32x4 __attribute__((ext_vector_type(4)));

template <int I> struct IC { static constexpr int value = I; };
template <int I, int N, typename F>
__device__ __forceinline__ void sfor(F&& f) {
  if constexpr (I < N) { f(IC<I>{}); sfor<I + 1, N>((F&&)f); }
}

__device__ __forceinline__ short f2bf(float x) {
  return __builtin_bit_cast(short, (__bf16)x);
}
__device__ __forceinline__ float bf2f(short u) {
  return __uint_as_float(((unsigned)(unsigned short)u) << 16);
}

// async DMA one 1KB segment: 64 lanes x 16B, LDS dest = uniform base + lane*16
__device__ __forceinline__ void stage_tile(const short* g, short* l) {
#pragma unroll
  for (int s = 0; s < 4; ++s) {
    __builtin_amdgcn_global_load_lds(
        (const __attribute__((address_space(1))) void*)(g + (s << 9)),
        (__attribute__((address_space(3))) void*)(l + (s << 9)), 16, 0, 0);
  }
}

// ---- prep: Khi = bf16(K) in MFMA B-fragment order ----
// Frag (b,ct,s,lane): lane(quad,m16) holds K[b][ct*16+m16][s*32+quad*8 .. +8]
__global__ __launch_bounds__(256)
void ksplit(const float* __restrict__ K, short* __restrict__ Khi) {
  const int lin  = blockIdx.x * 256 + threadIdx.x;   // 262144 frags
  const int b    = lin >> 15;
  const int rem  = lin & 32767;
  const int ct   = rem >> 8;
  const int s    = (rem >> 6) & 3;
  const int lane = rem & 63;
  const int quad = lane >> 4, m16 = lane & 15;
  const size_t elem = (size_t)(b * SS + ct * 16 + m16) * DD + s * 32 + quad * 8;
  const float4 v0 = *(const float4*)(K + elem);
  const float4 v1 = *(const float4*)(K + elem + 4);
  const float f[8] = {v0.x, v0.y, v0.z, v0.w, v1.x, v1.y, v1.z, v1.w};
  bf16x8 h;
#pragma unroll
  for (int e = 0; e < 8; ++e) h[e] = f2bf(f[e]);
  *(bf16x8*)(Khi + (size_t)lin * 8) = h;      // fragment order
}

// ---- fused entmax attention ----
// two half-passes over col-tiles with acc[8] (32 AGPR) so total regs fit 128/wave
// (waves_per_eu(4) -> 4 waves/SIMD, 2 blocks/CU) with NO scratch spill.
__global__ __launch_bounds__(512) __attribute__((amdgpu_waves_per_eu(4)))
void attn(const float* __restrict__ Q, const short* __restrict__ Khi,
          const float* __restrict__ K, const float* __restrict__ V,
          float* __restrict__ Out) {
  __shared__ short kring[NW][2][2048];         // per-wave 2-slot tile ring (64 KiB)
  __shared__ unsigned short Qs[ROWS][136];     // bf16(0.5*Q), A-operand layout
  __shared__ float rbuf[ROWS][64];             // candidate VALUES (then exact)
  __shared__ int   scol[ROWS][64];             // candidate COLUMNS
  __shared__ float exM0[NW][ROWS];
  __shared__ float exM1[NW][ROWS];
  __shared__ int   rcnt[ROWS];
  __shared__ int   rovf[ROWS];                 // per-row overflow flag
  __shared__ float tauB[ROWS], ZB[ROWS];

  const int tid  = threadIdx.x;
  const int lane = tid & 63;
  const int wid  = __builtin_amdgcn_readfirstlane(tid >> 6);  // 0..7
  const int quad = lane >> 4, m16 = lane & 15;
  const int b    = blockIdx.x & 7;             // batch -> XCD pinning
  const int qt   = blockIdx.x >> 3;            // 0..127

  const float* Qb = Q + (size_t)(b * SS + qt * ROWS) * DD;
  const float* Kb = K + (size_t)b * SS * DD;
  const float* Vb = V + (size_t)b * SS * DD;
  float*       Ob = Out + (size_t)(b * SS + qt * ROWS) * DD;
  const short* KHb = Khi + (size_t)b * SS * DD;

  if (tid < ROWS) { rcnt[tid] = 0; rovf[tid] = 0; }

  // ---- stage Q once: bf16(0.5*q), A-operand layout ----
  {
    const int row = tid >> 5, d = (tid & 31) * 4;
    const float4 v = *(const float4*)&Qb[row * DD + d];
    ushort4 h;
    h.x = (unsigned short)f2bf(0.5f * v.x);
    h.y = (unsigned short)f2bf(0.5f * v.y);
    h.z = (unsigned short)f2bf(0.5f * v.z);
    h.w = (unsigned short)f2bf(0.5f * v.w);
    *(ushort4*)&Qs[row][d] = h;
  }
  __syncthreads();   // also drains vmcnt -> ring counting below starts clean

  bf16x8 qh[4];
#pragma unroll
  for (int s = 0; s < 4; ++s)
    qh[s] = *(const bf16x8*)&Qs[m16][s * 32 + quad * 8];

  // ---- phase 1: z_a = bf16(0.5Q) * Khi^T via per-wave async LDS ring ----
  // wave 'wid' owns tiles ct = wid*16 + i; tiles consumed only by loader wave.
  short* ring0 = &kring[wid][0][0];
  short* ring1 = &kring[wid][1][0];
  const short* gw = KHb + ((size_t)(wid * CTW) << 11) + lane * 8;

  stage_tile(gw + 0 * 2048, ring0);
  stage_tile(gw + 1 * 2048, ring1);

  f32x4 acc[8];

  // ======== half 0: tiles 0..7 ========
  sfor<0, 8>([&](auto ic) {
    constexpr int i = ic.value;
    asm volatile("s_waitcnt vmcnt(4)" ::: "memory");
    const short* sbl = ((i & 1) ? ring1 : ring0) + lane * 8;
    f32x4 c = {0.f, 0.f, 0.f, 0.f};
    sfor<0, 4>([&](auto sc) {
      constexpr int s = sc.value;
      const bf16x8 bh = *(const bf16x8*)(sbl + (s << 9));
      c = __builtin_amdgcn_mfma_f32_16x16x32_bf16(qh[s], bh, c, 0, 0, 0);
    });
    acc[i] = c;
    asm volatile("s_waitcnt lgkmcnt(0)" ::: "memory");  // ds reads retired
    stage_tile(gw + (i + 2) * 2048, (i & 1) ? ring1 : ring0);
  });

  // half-0 row max -> M0
  {
    float mx[4] = {-1e38f, -1e38f, -1e38f, -1e38f};
    sfor<0, 8>([&](auto ic) {
#pragma unroll
      for (int j = 0; j < 4; ++j) mx[j] = fmaxf(mx[j], acc[ic.value][j]);
    });
#pragma unroll
    for (int j = 0; j < 4; ++j)
#pragma unroll
      for (int s = 1; s <= 8; s <<= 1) mx[j] = fmaxf(mx[j], __shfl_xor(mx[j], s));
    if (m16 == 0) {
#pragma unroll
      for (int j = 0; j < 4; ++j) exM0[wid][4 * quad + j] = mx[j];
    }
  }
  __syncthreads();   // drains vmcnt: tiles 8,9 land in ring
  float M0[4];
#pragma unroll
  for (int j = 0; j < 4; ++j) {
    float m = -1e38f;
#pragma unroll
    for (int w = 0; w < NW; ++w) m = fmaxf(m, exM0[w][4 * quad + j]);
    M0[j] = m;
  }
  // compact half-0 candidates (screen vs half-max is looser than global -> safe)
  sfor<0, 8>([&](auto ic) {
    constexpr int i = ic.value;
    const int col = wid * 256 + i * 16 + m16;
#pragma unroll
    for (int j = 0; j < 4; ++j) {
      const int row = 4 * quad + j;
      if (acc[i][j] > M0[j] - 1.25f) {
        const int pos = atomicAdd(&rcnt[row], 1);
        if (pos < 64) { scol[row][pos] = col; rbuf[row][pos] = acc[i][j]; }
        else rovf[row] = 1;
      }
    }
  });

  // ======== half 1: tiles 8..15 (reuse acc) ========
  sfor<8, 16>([&](auto ic) {
    constexpr int i = ic.value;
    if constexpr (i < 15) asm volatile("s_waitcnt vmcnt(4)" ::: "memory");
    else                  asm volatile("s_waitcnt vmcnt(0)" ::: "memory");
    const short* sbl = ((i & 1) ? ring1 : ring0) + lane * 8;
    f32x4 c = {0.f, 0.f, 0.f, 0.f};
    sfor<0, 4>([&](auto sc) {
      constexpr int s = sc.value;
      const bf16x8 bh = *(const bf16x8*)(sbl + (s << 9));
      c = __builtin_amdgcn_mfma_f32_16x16x32_bf16(qh[s], bh, c, 0, 0, 0);
    });
    acc[i - 8] = c;
    if constexpr (i + 2 < 16) {
      asm volatile("s_waitcnt lgkmcnt(0)" ::: "memory");
      stage_tile(gw + (i + 2) * 2048, (i & 1) ? ring1 : ring0);
    }
  });

  // half-1 row max -> M1
  {
    float mx[4] = {-1e38f, -1e38f, -1e38f, -1e38f};
    sfor<0, 8>([&](auto ic) {
#pragma unroll
      for (int j = 0; j < 4; ++j) mx[j] = fmaxf(mx[j], acc[ic.value][j]);
    });
#pragma unroll
    for (int j = 0; j < 4; ++j)
#pragma unroll
      for (int s = 1; s <= 8; s <<= 1) mx[j] = fmaxf(mx[j], __shfl_xor(mx[j], s));
    if (m16 == 0) {
#pragma unroll
      for (int j = 0; j < 4; ++j) exM1[wid][4 * quad + j] = mx[j];
    }
  }
  __syncthreads();
  float M1[4];
#pragma unroll
  for (int j = 0; j < 4; ++j) {
    float m = -1e38f;
#pragma unroll
    for (int w = 0; w < NW; ++w) m = fmaxf(m, exM1[w][4 * quad + j]);
    M1[j] = m;
  }
  sfor<0, 8>([&](auto ic) {
    constexpr int i = ic.value;
    const int col = wid * 256 + (i + 8) * 16 + m16;
#pragma unroll
    for (int j = 0; j < 4; ++j) {
      const int row = 4 * quad + j;
      if (acc[i][j] > M1[j] - 1.25f) {
        const int pos = atomicAdd(&rcnt[row], 1);
        if (pos < 64) { scol[row][pos] = col; rbuf[row][pos] = acc[i][j]; }
        else rovf[row] = 1;
      }
    }
  });
  __syncthreads();   // candidate tables complete; acc dead from here

  // ======== everything below is wave-local: wave wid owns rows 2*wid, 2*wid+1 ========

  // ---- refine candidates EXACTLY: z = 0.5 * dot_f32(Q[row], K[c]) ----
#pragma unroll
  for (int rr = 0; rr < 2; ++rr) {
    const int row = 2 * wid + rr;
    if (rovf[row]) continue;
    const int n = rcnt[row];
    const float2 q2 = *(const float2*)&Qb[row * DD + lane * 2];
    for (int i = 0; i < n; ++i) {
      const int c = scol[row][i];
      const float2 k2 = *(const float2*)&Kb[(size_t)c * DD + lane * 2];
      float t = fmaf(q2.x, k2.x, q2.y * k2.y);
#pragma unroll
      for (int s = 1; s <= 32; s <<= 1) t += __shfl_xor(t, s);
      if (lane == 0) rbuf[row][i] = 0.5f * t;
    }
  }

  // ---- fast bisection: 32 lanes per row, candidates in 2 registers ----
  {
    const int rr32 = lane >> 5;                 // 0/1 -> which of this wave's rows
    const int row  = 2 * wid + rr32;
    const int l32  = lane & 31;
    const int n = rcnt[row] < 64 ? rcnt[row] : 64;
    const float a0 = (l32 < n)      ? rbuf[row][l32]      : -1e38f;
    const float a1 = (l32 + 32 < n) ? rbuf[row][l32 + 32] : -1e38f;
    float Mr = fmaxf(a0, a1);
#pragma unroll
    for (int s = 1; s <= 16; s <<= 1) Mr = fmaxf(Mr, __shfl_xor(Mr, s));
    float tmn = Mr - 1.0f, tmx = Mr - 0.022097086912079608f;  // S^(1-alpha)
    float tau = 0.5f * (tmn + tmx), Zr = 0.f;
    for (int it = 0; it < 100; ++it) {
      tau = 0.5f * (tmn + tmx);
      const float t0 = fmaxf(a0 - tau, 0.f);
      const float t1 = fmaxf(a1 - tau, 0.f);
      float zp = fmaf(t0, t0, t1 * t1);
#pragma unroll
      for (int s = 1; s <= 16; s <<= 1) zp += __shfl_xor(zp, s);
      Zr = zp;
      const float nmn = (zp >= 1.f) ? tau : tmn;
      const float nmx = (zp >= 1.f) ? tmx : tau;
      const bool ch = (nmn != tmn) || (nmx != tmx);
      tmn = nmn; tmx = nmx;
      if (!__any(ch)) break;   // fixed point: faithful to 100 iters
    }
    if (l32 == 0) { tauB[row] = tau; ZB[row] = Zr; }
  }
  // tauB/ZB/rbuf written+read by this same wave only -> no barrier

  // ---- output per row ----
#pragma unroll
  for (int rr = 0; rr < 2; ++rr) {
    const int row = 2 * wid + rr;
    if (!rovf[row]) {
      // fast: O = sum p_i * V[col_i]; p recomputed from LDS broadcast
      const int n = rcnt[row];
      const float tau = tauB[row];
      const float iz  = 1.0f / ZB[row];
      float2 o = {0.f, 0.f};
      for (int i = 0; i < n; ++i) {
        const float rv = rbuf[row][i];          // same addr all lanes -> broadcast
        const float tt = fmaxf(rv - tau, 0.f);
        const float pi = tt * tt * iz;
        const int   c  = scol[row][i];
        const float2 v2 = *(const float2*)&Vb[(size_t)c * DD + lane * 2];
        o.x = fmaf(pi, v2.x, o.x);
        o.y = fmaf(pi, v2.y, o.y);
      }
      *(float2*)&Ob[row * DD + lane * 2] = o;
    } else {
      // ---- exact wave-local dense fallback (candidate overflow; ~unreachable) ----
      float* zr = (float*)&kring[wid][0][0];    // 2048 f32, wave-private dead ring
      for (int c0 = 0; c0 < 32; ++c0) {
        const int c = c0 * 64 + lane;
        const float* kp = &Kb[(size_t)c * DD];
        float t = 0.f;
        for (int d = 0; d < DD; d += 4) {
          const float4 qv = *(const float4*)&Qb[row * DD + d];
          const float4 kv = *(const float4*)&kp[d];
          t = fmaf(qv.x, kv.x, t); t = fmaf(qv.y, kv.y, t);
          t = fmaf(qv.z, kv.z, t); t = fmaf(qv.w, kv.w, t);
        }
        zr[c] = 0.5f * t;
      }
      float Mr = -1e38f;
      for (int c0 = 0; c0 < 32; ++c0) Mr = fmaxf(Mr, zr[c0 * 64 + lane]);
#pragma unroll
      for (int s = 1; s <= 32; s <<= 1) Mr = fmaxf(Mr, __shfl_xor(Mr, s));
      float tmn = Mr - 1.0f, tmx = Mr - 0.022097086912079608f;
      float tau = 0.5f * (tmn + tmx), Zr = 0.f;
      for (int it = 0; it < 100; ++it) {
        tau = 0.5f * (tmn + tmx);
        float zp = 0.f;
        for (int c0 = 0; c0 < 32; ++c0) {
          const float tt = fmaxf(zr[c0 * 64 + lane] - tau, 0.f);
          zp = fmaf(tt, tt, zp);
        }
#pragma unroll
        for (int s = 1; s <= 32; s <<= 1) zp += __shfl_xor(zp, s);
        Zr = zp;
        const float nmn = (zp >= 1.f) ? tau : tmn;
        const float nmx = (zp >= 1.f) ? tmx : tau;
        const bool ch = (nmn != tmn) || (nmx != tmx);
        tmn = nmn; tmx = nmx;
        if (!__any(ch)) break;
      }
      const float iz = 1.0f / Zr;
      float2 o = {0.f, 0.f};
      for (int c = 0; c < SS; ++c) {
        const float tt = fmaxf(zr[c] - tau, 0.f);   // broadcast -> uniform branch
        if (tt > 0.f) {
          const float pi = tt * tt * iz;
          const float2 v2 = *(const float2*)&Vb[(size_t)c * DD + lane * 2];
          o.x = fmaf(pi, v2.x, o.x);
          o.y = fmaf(pi, v2.y, o.y);
        }
      }
      *(float2*)&Ob[row * DD + lane * 2] = o;
    }
  }
}

extern "C" void kernel_launch(void* const* d_in, const int* in_sizes, int n_in,
                              void* d_out, int out_size, void* d_ws, size_t ws_size,
                              hipStream_t stream) {
  const float* Q = (const float*)d_in[0];
  const float* K = (const float*)d_in[1];
  const float* V = (const float*)d_in[2];
  float* out = (float*)d_out;
  short* Khi = (short*)d_ws;                      // 4 MiB, fragment order

  hipLaunchKernelGGL(ksplit, dim3(BB * SS * DD / (256 * 8)), dim3(256), 0, stream,
                     K, Khi);
  hipLaunchKernelGGL(attn, dim3(BB * (SS / ROWS)), dim3(512), 0, stream,
                     Q, Khi, K, V, out);
}

// Round 4
// 127.973 us; speedup vs baseline: 1.1119x; 1.1119x over previous
//
#include <hip/hip_runtime.h>

#define BB 8
#define SS 2048
#define DD 128
#define ROWS 16            // q rows per block
#define NW 8               // waves per block (512 threads)
#define CTW 16             // col-tiles (of 16) per wave -> 256 cols/wave

typedef short bf16x8 __attribute__((ext_vector_type(8)));
typedef float f32x4 __attribute__((ext_vector_type(4)));

template <int I> struct IC { static constexpr int value = I; };
template <int I, int N, typename F>
__device__ __forceinline__ void sfor(F&& f) {
  if constexpr (I < N) { f(IC<I>{}); sfor<I + 1, N>((F&&)f); }
}

__device__ __forceinline__ short f2bf(float x) {
  return __builtin_bit_cast(short, (__bf16)x);
}
__device__ __forceinline__ float bf2f(short u) {
  return __uint_as_float(((unsigned)(unsigned short)u) << 16);
}
__device__ __forceinline__ unsigned pk2(float a, float b) {
  return (unsigned)(unsigned short)f2bf(a) |
         ((unsigned)(unsigned short)f2bf(b) << 16);
}

template <int N> __device__ __forceinline__ void wait_vm() {
  if constexpr (N >= 6)      asm volatile("s_waitcnt vmcnt(6)" ::: "memory");
  else if constexpr (N == 5) asm volatile("s_waitcnt vmcnt(5)" ::: "memory");
  else if constexpr (N == 4) asm volatile("s_waitcnt vmcnt(4)" ::: "memory");
  else if constexpr (N == 3) asm volatile("s_waitcnt vmcnt(3)" ::: "memory");
  else if constexpr (N == 2) asm volatile("s_waitcnt vmcnt(2)" ::: "memory");
  else if constexpr (N == 1) asm volatile("s_waitcnt vmcnt(1)" ::: "memory");
  else                       asm volatile("s_waitcnt vmcnt(0)" ::: "memory");
}

// async DMA one 1KB quarter-tile: 64 lanes x 16B, LDS dest = uniform base + lane*16
__device__ __forceinline__ void stage1(const short* g, short* l) {
  __builtin_amdgcn_global_load_lds(
      (const __attribute__((address_space(1))) void*)g,
      (__attribute__((address_space(3))) void*)l, 16, 0, 0);
}

// ---- prep: Khi = bf16(K) in MFMA B-fragment order ----
// Frag (b,ct,s,lane): lane(quad,m16) holds K[b][ct*16+m16][s*32+quad*8 .. +8]
__global__ __launch_bounds__(256)
void ksplit(const float* __restrict__ K, short* __restrict__ Khi) {
  const int lin  = blockIdx.x * 256 + threadIdx.x;   // 262144 frags
  const int b    = lin >> 15;
  const int rem  = lin & 32767;
  const int ct   = rem >> 8;
  const int s    = (rem >> 6) & 3;
  const int lane = rem & 63;
  const int quad = lane >> 4, m16 = lane & 15;
  const size_t elem = (size_t)(b * SS + ct * 16 + m16) * DD + s * 32 + quad * 8;
  const float4 v0 = *(const float4*)(K + elem);
  const float4 v1 = *(const float4*)(K + elem + 4);
  const float f[8] = {v0.x, v0.y, v0.z, v0.w, v1.x, v1.y, v1.z, v1.w};
  bf16x8 h;
#pragma unroll
  for (int e = 0; e < 8; ++e) h[e] = f2bf(f[e]);
  *(bf16x8*)(Khi + (size_t)lin * 8) = h;      // fragment order
}

// ---- fused entmax attention ----
// deep-ring async screen (8x1KB slots, 7-ahead, stage-before-read) + packed-bf16
// z_a in 32 VGPRs + exact fp32 candidate refine + 2-rows-parallel tail.
__global__ __launch_bounds__(512) __attribute__((amdgpu_waves_per_eu(4)))
void attn(const float* __restrict__ Q, const short* __restrict__ Khi,
          const float* __restrict__ K, const float* __restrict__ V,
          float* __restrict__ Out) {
  __shared__ short kring[NW][8][512];          // per-wave 8-slot 1KB ring (64 KiB)
  __shared__ unsigned short Qs[ROWS][136];     // bf16(0.5*Q), A-operand layout
  __shared__ float rbuf[ROWS][64];             // candidate VALUES (then exact)
  __shared__ int   scol[ROWS][64];             // candidate COLUMNS
  __shared__ float exM[NW][ROWS];
  __shared__ int   rcnt[ROWS];
  __shared__ int   rovf[ROWS];                 // per-row overflow flag
  __shared__ float tauB[ROWS], ZB[ROWS];

  const int tid  = threadIdx.x;
  const int lane = tid & 63;
  const int wid  = __builtin_amdgcn_readfirstlane(tid >> 6);  // 0..7
  const int quad = lane >> 4, m16 = lane & 15;
  const int b    = blockIdx.x & 7;             // batch -> XCD pinning
  const int qt   = blockIdx.x >> 3;            // 0..127

  const float* Qb = Q + (size_t)(b * SS + qt * ROWS) * DD;
  const float* Kb = K + (size_t)b * SS * DD;
  const float* Vb = V + (size_t)b * SS * DD;
  float*       Ob = Out + (size_t)(b * SS + qt * ROWS) * DD;
  const short* KHb = Khi + (size_t)b * SS * DD;

  if (tid < ROWS) { rcnt[tid] = 0; rovf[tid] = 0; }

  // ---- stage Q once: bf16(0.5*q), A-operand layout ----
  {
    const int row = tid >> 5, d = (tid & 31) * 4;
    const float4 v = *(const float4*)&Qb[row * DD + d];
    ushort4 h;
    h.x = (unsigned short)f2bf(0.5f * v.x);
    h.y = (unsigned short)f2bf(0.5f * v.y);
    h.z = (unsigned short)f2bf(0.5f * v.z);
    h.w = (unsigned short)f2bf(0.5f * v.w);
    *(ushort4*)&Qs[row][d] = h;
  }
  __syncthreads();   // also drains vmcnt -> ring counting below starts clean

  bf16x8 qh[4];
#pragma unroll
  for (int s = 0; s < 4; ++s)
    qh[s] = *(const bf16x8*)&Qs[m16][s * 32 + quad * 8];

  // ---- phase 1: z_a = bf16(0.5Q) * Khi^T, 64 quarter-tiles (1KB each) ----
  // quarter-tile q = (col-tile q>>2, k-slice q&3). 8-slot ring, 7-ahead.
  // iter q: wait vmcnt(min(6,63-q)) [tile q landed]; lgkmcnt(0) [slot (q-1)&7
  // reads retired, ~free]; stage q+7 -> slot (q+7)&7 = (q-1)&7; ds_read slot q&7;
  // MFMA. Steady-state stall ~0.
  short* ring = &kring[wid][0][0];
  const short* gw = KHb + ((size_t)(wid * CTW) << 11) + lane * 8;  // +q*512 shorts

  sfor<0, 7>([&](auto pc) {
    constexpr int p = pc.value;
    stage1(gw + p * 512, ring + p * 512);
  });

  unsigned zpk[CTW][2];                        // packed bf16 z_a, 32 VGPRs
  float mx[4] = {-1e38f, -1e38f, -1e38f, -1e38f};
  f32x4 acc = {0.f, 0.f, 0.f, 0.f};

  sfor<0, 64>([&](auto qc) {
    constexpr int q = qc.value;
    wait_vm<(63 - q < 6 ? 63 - q : 6)>();
    asm volatile("s_waitcnt lgkmcnt(0)" ::: "memory");
    if constexpr (q + 7 < 64)
      stage1(gw + (q + 7) * 512, ring + ((q + 7) & 7) * 512);
    const bf16x8 bh = *(const bf16x8*)(ring + ((q & 7) << 9) + lane * 8);
    constexpr int s = q & 3;
    if constexpr (s == 0) acc = f32x4{0.f, 0.f, 0.f, 0.f};
    acc = __builtin_amdgcn_mfma_f32_16x16x32_bf16(qh[s], bh, acc, 0, 0, 0);
    if constexpr (s == 3) {
      constexpr int ct = q >> 2;
#pragma unroll
      for (int j = 0; j < 4; ++j) mx[j] = fmaxf(mx[j], acc[j]);
      zpk[ct][0] = pk2(acc[0], acc[1]);
      zpk[ct][1] = pk2(acc[2], acc[3]);
    }
  });
  // lane holds packed z_a[row=4*quad+j][col = wid*256 + ct*16 + m16]

  // ---- cross-wave row max ----
#pragma unroll
  for (int j = 0; j < 4; ++j)
#pragma unroll
    for (int s = 1; s <= 8; s <<= 1) mx[j] = fmaxf(mx[j], __shfl_xor(mx[j], s));
  if (m16 == 0) {
#pragma unroll
    for (int j = 0; j < 4; ++j) exM[wid][4 * quad + j] = mx[j];
  }
  __syncthreads();
  float M4[4];
#pragma unroll
  for (int j = 0; j < 4; ++j) {
    float m = -1e38f;
#pragma unroll
    for (int w = 0; w < NW; ++w) m = fmaxf(m, exM[w][4 * quad + j]);
    M4[j] = m;
  }

  // ---- compact candidates: z_pk > M - 1.35 (1 + screen err + pack rounding) ----
  sfor<0, CTW>([&](auto cc) {
    constexpr int ct = cc.value;
    const int col = wid * 256 + ct * 16 + m16;
    float v[4];
    v[0] = __uint_as_float(zpk[ct][0] << 16);
    v[1] = __uint_as_float(zpk[ct][0] & 0xffff0000u);
    v[2] = __uint_as_float(zpk[ct][1] << 16);
    v[3] = __uint_as_float(zpk[ct][1] & 0xffff0000u);
#pragma unroll
    for (int j = 0; j < 4; ++j) {
      const int row = 4 * quad + j;
      if (v[j] > M4[j] - 1.35f) {
        const int pos = atomicAdd(&rcnt[row], 1);
        if (pos < 64) { scol[row][pos] = col; rbuf[row][pos] = v[j]; }
        else rovf[row] = 1;
      }
    }
  });
  __syncthreads();   // candidate tables complete

  // ======== wave-local tail: wave wid owns rows 2*wid, 2*wid+1 ========
  const int rr32 = lane >> 5;                  // which of this wave's rows
  const int row  = 2 * wid + rr32;
  const int l32  = lane & 31;
  const int nA = rcnt[2 * wid]     < 64 ? rcnt[2 * wid]     : 64;
  const int nB = rcnt[2 * wid + 1] < 64 ? rcnt[2 * wid + 1] : 64;
  const int nr  = rr32 ? nB : nA;
  const int nmx = nA > nB ? nA : nB;

  // ---- refine EXACTLY (both rows in parallel, 32 lanes each): z = 0.5*dot ----
  {
    const float4 q4 = *(const float4*)&Qb[row * DD + l32 * 4];
    for (int i = 0; i < nmx; ++i) {
      const bool act = i < nr;
      const int c = act ? scol[row][i] : scol[row][0];
      const float4 k4 = *(const float4*)&Kb[(size_t)c * DD + l32 * 4];
      float t = q4.x * k4.x + q4.y * k4.y + q4.z * k4.z + q4.w * k4.w;
#pragma unroll
      for (int s = 1; s <= 16; s <<= 1) t += __shfl_xor(t, s);
      if (act && l32 == 0) rbuf[row][i] = 0.5f * t;
    }
  }
  // rbuf written+read by this same wave only -> no barrier

  // ---- bisection: 32 lanes per row, candidates in 2 registers ----
  {
    const float a0 = (l32 < nr)      ? rbuf[row][l32]      : -1e38f;
    const float a1 = (l32 + 32 < nr) ? rbuf[row][l32 + 32] : -1e38f;
    float Mr = fmaxf(a0, a1);
#pragma unroll
    for (int s = 1; s <= 16; s <<= 1) Mr = fmaxf(Mr, __shfl_xor(Mr, s));
    float tmn = Mr - 1.0f, tmx = Mr - 0.022097086912079608f;  // S^(1-alpha)
    float tau = 0.5f * (tmn + tmx), Zr = 0.f;
    for (int it = 0; it < 100; ++it) {
      tau = 0.5f * (tmn + tmx);
      const float t0 = fmaxf(a0 - tau, 0.f);
      const float t1 = fmaxf(a1 - tau, 0.f);
      float zp = fmaf(t0, t0, t1 * t1);
#pragma unroll
      for (int s = 1; s <= 16; s <<= 1) zp += __shfl_xor(zp, s);
      Zr = zp;
      const float nmn = (zp >= 1.f) ? tau : tmn;
      const float nmx = (zp >= 1.f) ? tmx : tau;
      const bool ch = (nmn != tmn) || (nmx != tmx);
      tmn = nmn; tmx = nmx;
      if (!__any(ch)) break;   // fixed point: faithful to 100 iters
    }
    if (l32 == 0) { tauB[row] = tau; ZB[row] = Zr; }
  }

  // ---- fast output (both rows in parallel): O = sum p_i * V[col_i] ----
  if (!rovf[row]) {
    const float tau = tauB[row];
    const float iz  = 1.0f / ZB[row];
    float4 o = {0.f, 0.f, 0.f, 0.f};
    for (int i = 0; i < nr; ++i) {
      const float rv = rbuf[row][i];           // same addr per half -> broadcast
      const float tt = fmaxf(rv - tau, 0.f);
      const float pi = tt * tt * iz;
      const int   c  = scol[row][i];
      const float4 v4 = *(const float4*)&Vb[(size_t)c * DD + l32 * 4];
      o.x = fmaf(pi, v4.x, o.x);
      o.y = fmaf(pi, v4.y, o.y);
      o.z = fmaf(pi, v4.z, o.z);
      o.w = fmaf(pi, v4.w, o.w);
    }
    *(float4*)&Ob[row * DD + l32 * 4] = o;
  }

  // ---- exact wave-local dense fallback (candidate overflow; ~unreachable) ----
#pragma unroll
  for (int rr = 0; rr < 2; ++rr) {
    const int frow = 2 * wid + rr;
    if (!rovf[frow]) continue;
    float* zr = (float*)&kring[wid][0][0];     // 8 KB = 2048 f32, wave-private
    for (int c0 = 0; c0 < 32; ++c0) {
      const int c = c0 * 64 + lane;
      const float* kp = &Kb[(size_t)c * DD];
      float t = 0.f;
      for (int d = 0; d < DD; d += 4) {
        const float4 qv = *(const float4*)&Qb[frow * DD + d];
        const float4 kv = *(const float4*)&kp[d];
        t = fmaf(qv.x, kv.x, t); t = fmaf(qv.y, kv.y, t);
        t = fmaf(qv.z, kv.z, t); t = fmaf(qv.w, kv.w, t);
      }
      zr[c] = 0.5f * t;
    }
    float Mr = -1e38f;
    for (int c0 = 0; c0 < 32; ++c0) Mr = fmaxf(Mr, zr[c0 * 64 + lane]);
#pragma unroll
    for (int s = 1; s <= 32; s <<= 1) Mr = fmaxf(Mr, __shfl_xor(Mr, s));
    float tmn = Mr - 1.0f, tmx = Mr - 0.022097086912079608f;
    float tau = 0.5f * (tmn + tmx), Zr = 0.f;
    for (int it = 0; it < 100; ++it) {
      tau = 0.5f * (tmn + tmx);
      float zp = 0.f;
      for (int c0 = 0; c0 < 32; ++c0) {
        const float tt = fmaxf(zr[c0 * 64 + lane] - tau, 0.f);
        zp = fmaf(tt, tt, zp);
      }
#pragma unroll
      for (int s = 1; s <= 32; s <<= 1) zp += __shfl_xor(zp, s);
      Zr = zp;
      const float nmn = (zp >= 1.f) ? tau : tmn;
      const float nmx = (zp >= 1.f) ? tmx : tau;
      const bool ch = (nmn != tmn) || (nmx != tmx);
      tmn = nmn; tmx = nmx;
      if (!__any(ch)) break;
    }
    const float iz = 1.0f / Zr;
    float2 o = {0.f, 0.f};
    for (int c = 0; c < SS; ++c) {
      const float tt = fmaxf(zr[c] - tau, 0.f);   // broadcast -> uniform branch
      if (tt > 0.f) {
        const float pi = tt * tt * iz;
        const float2 v2 = *(const float2*)&Vb[(size_t)c * DD + lane * 2];
        o.x = fmaf(pi, v2.x, o.x);
        o.y = fmaf(pi, v2.y, o.y);
      }
    }
    *(float2*)&Ob[frow * DD + lane * 2] = o;
  }
}

extern "C" void kernel_launch(void* const* d_in, const int* in_sizes, int n_in,
                              void* d_out, int out_size, void* d_ws, size_t ws_size,
                              hipStream_t stream) {
  const float* Q = (const float*)d_in[0];
  const float* K = (const float*)d_in[1];
  const float* V = (const float*)d_in[2];
  float* out = (float*)d_out;
  short* Khi = (short*)d_ws;                      // 4 MiB, fragment order

  hipLaunchKernelGGL(ksplit, dim3(BB * SS * DD / (256 * 8)), dim3(256), 0, stream,
                     K, Khi);
  hipLaunchKernelGGL(attn, dim3(BB * (SS / ROWS)), dim3(512), 0, stream,
                     Q, Khi, K, V, out);
}